// Round 9
// baseline (412.784 us; speedup 1.0000x reference)
//
#include <hip/hip_runtime.h>

// GRU (B=4096, T=2048, H=8, I=4) + fused FC (O=4), fp32.
// R11: VOP2-maximal rewrite. Refined issue law (fits R5/R6/R10 busy
// counters): VOP1/VOP2 = 2 cyc, VOP3/VOP3P = 4 cyc (operand-delivery
// limited), trans = 8 cyc per wave64 inst. R10's v_pk_fma_f32 (4 cyc, 2
// FLOPs) therefore ties two v_fmac_f32 (2x2 cyc) -- packing saved
// instructions, not issue cycles (busy 206 for 48 inst = 4.3 avg). This
// round re-expresses all dots as IN-PLACE fmac accumulation chains
// (acc = fmaf(w,h,acc), dst==src2 -> LLVM emits VOP2 v_fmac_f32):
//   - own-gate: xOwn 4-chain (h-independent) feeding two 4-deep h-chains
//     (caps h-dep latency ~20 cyc) + 1 add.
//   - n-dot / FC-dot: full 8-deep fmac chains (latency hidden under the
//     own-gate sigmoid's trans latency).
//   - tail keeps R10's u2 = rcp(fma(0.5,e,0.5)) = 2*u form (no -2*omz mul).
// Projected busy ~155-170 cyc/step vs R10's 206.
// Carried (verified R6/R10): gate-split r/z across the lane pair (one
// sigmoid per lane + ror8 exchange + 2 cndmask), row_ror:1..7 depth-1
// gather with (m-r)&7 pre-permuted weights, scale-folded sigmoid/tanh,
// lagged FC reusing the gather, ping-pong x prefetch, banked 16-dword
// stores.

#define GRU_T 2048
#define GRU_H 8
#define GRU_I 4
#define GRU_O 4
#define PFD   8        // per ping-pong half; 2*PFD must divide T

#define DPP_ROR(n) (0x120 + (n))   // row_ror:n : lane i <- lane (i-n)&15

template <int CTRL>
__device__ __forceinline__ float dpp_movf(float v) {
    return __int_as_float(
        __builtin_amdgcn_mov_dpp(__float_as_int(v), CTRL, 0xf, 0xf, true));
}

__device__ __forceinline__ float fast_rcp(float x)  { return __builtin_amdgcn_rcpf(x); }
__device__ __forceinline__ float fast_exp2(float x) { return __builtin_amdgcn_exp2f(x); }

__global__ __launch_bounds__(64, 1) void gru_fc_kernel(
    const float* __restrict__ x,
    const float* __restrict__ W_ih,
    const float* __restrict__ W_hh,
    const float* __restrict__ b_ih,
    const float* __restrict__ b_hh,
    const float* __restrict__ W_fc,
    const float* __restrict__ b_fc,
    float* __restrict__ out)
{
    const int tid = blockIdx.x * 64 + (int)threadIdx.x;
    const int b   = tid >> 4;            // batch element (4 per wave)
    const int q   = tid & 15;            // lane within element (one DPP row)
    const int g   = (q >> 3) & 1;        // 0: r-gate lane, 1: z-gate lane
    const int m   = q & 7;               // hidden index this lane owns
    const int o   = q & 3;               // FC output index (4x duplicated)
    const bool hi = (q & 8) != 0;

    // scale folding: sigma(a) = rcp(1+exp2(SR*a)); 1-sigma(a) =
    // rcp(1+exp2(SZ*a)); tanh(y) = 1 - 2*rcp(1+exp2(SN*y))
    const float SR = -1.4426950408889634f;
    const float SZ =  1.4426950408889634f;
    const float SN =  2.8853900817779268f;

    const float SG   = g ? SZ : SR;      // own-gate scale
    const int   gate = g ? 1 : 0;        // own-gate row block in W_*h

    // ---- weights into registers, pre-permuted per lane ----
    float whA[8], whn[8], wf[8];
#pragma unroll
    for (int r = 0; r < 8; ++r) {
        const int k = (m - r) & 7;       // rot[r] holds h[(m-r)&7]
        whA[r] = SG * W_hh[(gate * GRU_H + m) * GRU_H + k];
        whn[r] = SN * W_hh[(2 * GRU_H + m) * GRU_H + k];
        wf[r]  = W_fc[o * GRU_H + k];
    }
    float wiA[4], win[4];
#pragma unroll
    for (int k = 0; k < 4; ++k) {
        wiA[k] = SG * W_ih[(gate * GRU_H + m) * GRU_I + k];
        win[k] = SN * W_ih[(2 * GRU_H + m) * GRU_I + k];
    }
    const float bA  = SG * (b_ih[gate * GRU_H + m] + b_hh[gate * GRU_H + m]);
    const float bxn = SN * b_ih[2 * GRU_H + m];
    const float bhn = SN * b_hh[2 * GRU_H + m];
    const float bo  = b_fc[o];

    float hprev = 0.0f;
    float bank0 = 0.0f, bank1 = 0.0f, bank2 = 0.0f;

    const float4* __restrict__ xp = reinterpret_cast<const float4*>(x) + (size_t)b * GRU_T;
    float* __restrict__ op = out + (size_t)b * GRU_T * GRU_O + q;

    float4 bufA[PFD], bufB[PFD];
#pragma unroll
    for (int j = 0; j < PFD; ++j) bufA[j] = xp[j];

#define GRU_STEP(XC, TCUR, JM)                                                 \
    do {                                                                       \
        const float4 xc = (XC);                                                \
        /* x-chains (VOP2 fmac), h-independent */                              \
        float xOwn = bA;                                                       \
        xOwn = fmaf(wiA[0], xc.x, xOwn); xOwn = fmaf(wiA[1], xc.y, xOwn);      \
        xOwn = fmaf(wiA[2], xc.z, xOwn); xOwn = fmaf(wiA[3], xc.w, xOwn);      \
        float xn_ = bxn;                                                       \
        xn_ = fmaf(win[0], xc.x, xn_);   xn_ = fmaf(win[1], xc.y, xn_);        \
        xn_ = fmaf(win[2], xc.z, xn_);   xn_ = fmaf(win[3], xc.w, xn_);        \
        const float onemh = 1.0f - hprev;                                      \
        /* depth-1 rotation gather: rk = h_prev[(m-k)&7] */                    \
        const float r1 = dpp_movf<DPP_ROR(1)>(hprev);                          \
        const float r2 = dpp_movf<DPP_ROR(2)>(hprev);                          \
        const float r3 = dpp_movf<DPP_ROR(3)>(hprev);                          \
        const float r4 = dpp_movf<DPP_ROR(4)>(hprev);                          \
        const float r5 = dpp_movf<DPP_ROR(5)>(hprev);                          \
        const float r6 = dpp_movf<DPP_ROR(6)>(hprev);                          \
        const float r7 = dpp_movf<DPP_ROR(7)>(hprev);                          \
        /* own-gate: two 4-deep fmac chains (g0 -> ar, g1 -> az) */            \
        float oA = xOwn;                                                       \
        oA = fmaf(whA[0], hprev, oA); oA = fmaf(whA[1], r1, oA);               \
        oA = fmaf(whA[2], r2, oA);    oA = fmaf(whA[3], r3, oA);               \
        float oB = whA[4] * r4;                                                \
        oB = fmaf(whA[5], r5, oB);    oB = fmaf(whA[6], r6, oB);               \
        oB = fmaf(whA[7], r7, oB);                                             \
        const float aOwn = oA + oB;                                            \
        /* one sigmoid per lane: g0 -> r, g1 -> omz = 1-z; exchange pair */    \
        const float sOwn = fast_rcp(1.0f + fast_exp2(aOwn));                   \
        const float sSib = dpp_movf<DPP_ROR(8)>(sOwn);                         \
        const float rg   = hi ? sSib : sOwn;                                   \
        const float omz  = hi ? sOwn : sSib;                                   \
        /* n-dot: 8-deep fmac chain (hidden under sigmoid trans latency) */    \
        float ahn = bhn;                                                       \
        ahn = fmaf(whn[0], hprev, ahn); ahn = fmaf(whn[1], r1, ahn);           \
        ahn = fmaf(whn[2], r2, ahn);    ahn = fmaf(whn[3], r3, ahn);           \
        ahn = fmaf(whn[4], r4, ahn);    ahn = fmaf(whn[5], r5, ahn);           \
        ahn = fmaf(whn[6], r6, ahn);    ahn = fmaf(whn[7], r7, ahn);           \
        /* lagged FC on h(t-1): 8-deep fmac chain */                           \
        float fcv = bo;                                                        \
        fcv = fmaf(wf[0], hprev, fcv);  fcv = fmaf(wf[1], r1, fcv);            \
        fcv = fmaf(wf[2], r2, fcv);     fcv = fmaf(wf[3], r3, fcv);            \
        fcv = fmaf(wf[4], r4, fcv);     fcv = fmaf(wf[5], r5, fcv);            \
        fcv = fmaf(wf[6], r6, fcv);     fcv = fmaf(wf[7], r7, fcv);            \
        /* tail: u2 = 2/(1+exp2(yn)); hn = c1 - omz*u2 */                      \
        const float c1 = fmaf(omz, onemh, hprev);                              \
        float yn = xn_;                                                        \
        yn = fmaf(rg, ahn, yn);                                                \
        const float e  = fast_exp2(yn);                                        \
        const float u2 = fast_rcp(fmaf(0.5f, e, 0.5f));                        \
        hprev = fmaf(-omz, u2, c1);                                            \
        /* bank fc by s=(t-1)&3; store 4 steps per 16-dword chunk */           \
        if (((JM) & 3) == 1)      bank0 = fcv;                                 \
        else if (((JM) & 3) == 2) bank1 = fcv;                                 \
        else if (((JM) & 3) == 3) bank2 = fcv;                                 \
        else if ((TCUR) != 0) {                                                \
            const float v01 = (q & 4) ? bank1 : bank0;                         \
            const float v23 = (q & 4) ? fcv   : bank2;                         \
            const float val = (q & 8) ? v23   : v01;                           \
            op[(size_t)((TCUR) - 4) * GRU_O] = val;                            \
        }                                                                      \
    } while (0)

    for (int tb = 0; tb < GRU_T; tb += 2 * PFD) {
#pragma unroll
        for (int j = 0; j < PFD; ++j) bufB[j] = xp[tb + PFD + j];
#pragma unroll
        for (int j = 0; j < PFD; ++j) GRU_STEP(bufA[j], tb + j, j);
        const int tn = (tb + 2 * PFD) & (GRU_T - 1);   // wrap; values unused
#pragma unroll
        for (int j = 0; j < PFD; ++j) bufA[j] = xp[tn + j];
#pragma unroll
        for (int j = 0; j < PFD; ++j) GRU_STEP(bufB[j], tb + PFD + j, j);
    }

    // epilogue: flush lagged FC for step T-1 (h = final hprev)
    {
        const float r1 = dpp_movf<DPP_ROR(1)>(hprev);
        const float r2 = dpp_movf<DPP_ROR(2)>(hprev);
        const float r3 = dpp_movf<DPP_ROR(3)>(hprev);
        const float r4 = dpp_movf<DPP_ROR(4)>(hprev);
        const float r5 = dpp_movf<DPP_ROR(5)>(hprev);
        const float r6 = dpp_movf<DPP_ROR(6)>(hprev);
        const float r7 = dpp_movf<DPP_ROR(7)>(hprev);
        float fcv = bo;
        fcv = fmaf(wf[0], hprev, fcv);  fcv = fmaf(wf[1], r1, fcv);
        fcv = fmaf(wf[2], r2, fcv);     fcv = fmaf(wf[3], r3, fcv);
        fcv = fmaf(wf[4], r4, fcv);     fcv = fmaf(wf[5], r5, fcv);
        fcv = fmaf(wf[6], r6, fcv);     fcv = fmaf(wf[7], r7, fcv);
        const float v01 = (q & 4) ? bank1 : bank0;
        const float v23 = (q & 4) ? fcv   : bank2;
        const float val = (q & 8) ? v23   : v01;
        op[(size_t)(GRU_T - 4) * GRU_O] = val;
    }
#undef GRU_STEP
}

extern "C" void kernel_launch(void* const* d_in, const int* in_sizes, int n_in,
                              void* d_out, int out_size, void* d_ws, size_t ws_size,
                              hipStream_t stream) {
    const float* x    = (const float*)d_in[0];
    const float* W_ih = (const float*)d_in[1];
    const float* W_hh = (const float*)d_in[2];
    const float* b_ih = (const float*)d_in[3];
    const float* b_hh = (const float*)d_in[4];
    const float* W_fc = (const float*)d_in[5];
    const float* b_fc = (const float*)d_in[6];
    float* out = (float*)d_out;

    const int B = in_sizes[0] / (GRU_T * GRU_I);   // 4096
    dim3 grid((unsigned)(B * 16 / 64)), block(64); // 16 lanes/elem, 1024 waves
    hipLaunchKernelGGL(gru_fc_kernel, grid, block, 0, stream,
                       x, W_ih, W_hh, b_ih, b_hh, W_fc, b_fc, out);
}